// Round 8
// baseline (270.128 us; speedup 1.0000x reference)
//
#include <hip/hip_runtime.h>
#include <math.h>

#define BB   128   // batch
#define WW   128   // window
#define FIN  64
#define NNODE 64
#define NE   4096
#define EDIM 16
#define NH   4
#define CDIM 32
#define HC   128   // NH*CDIM
#define FLATD 8192
#define HIDD 2048

// ws layout (float offsets)
#define OFF_H    0u         // h[B][64][128]          1,048,576 f  (dead after k2f)
#define OFF_P    1048576u   // fc1 partials [8][128][2048] = 2,097,152 f
#define OFF_XGB  3211264u   // xgat bf16 (ELU applied) [B][8192] u16 = 524,288 f
#define OFF_BK   4259840u   // bucket ints: bstart[80] + blist[4096]

typedef unsigned short u16;
typedef u16    u16x8  __attribute__((ext_vector_type(8)));
typedef u16    u16x4  __attribute__((ext_vector_type(4)));
typedef __bf16 bf16x8 __attribute__((ext_vector_type(8)));
typedef float  f32x4  __attribute__((ext_vector_type(4)));
typedef float  f32x16 __attribute__((ext_vector_type(16)));

__device__ __forceinline__ u16 f2bf(float f) {   // RNE fp32 -> bf16 bits
    unsigned u = __float_as_uint(f);
    u += 0x7fffu + ((u >> 16) & 1u);
    return (u16)(u >> 16);
}
__device__ __forceinline__ void hilo(float v, u16* h, u16* l) {
    u16 hh = f2bf(v);
    float hf = __uint_as_float(((unsigned)hh) << 16);
    *h = hh;
    *l = f2bf(v - hf);
}

// ---------------- K0: bucket edges by destination (graph shared across batch) ----
// blist entry: (e<<12)|(d<<6)|s
__global__ __launch_bounds__(256) void k0_bucket(
        const int* __restrict__ ei, int* __restrict__ bstart, int* __restrict__ blist)
{
    __shared__ int cnt[64];
    __shared__ int cur[65];
    const int t = threadIdx.x;
    if (t < 64) cnt[t] = 0;
    __syncthreads();
    for (int e = t; e < NE; e += 256) atomicAdd(&cnt[ei[NE + e]], 1);
    __syncthreads();
    if (t == 0) {
        int run = 0;
        for (int n = 0; n < 64; ++n) { cur[n] = run; run += cnt[n]; }
        cur[64] = run;
    }
    __syncthreads();
    if (t < 65) bstart[t] = cur[t];
    __syncthreads();
    for (int e = t; e < NE; e += 256) {
        int d = ei[NE + e], s = ei[e];
        int p = atomicAdd(&cur[d], 1);
        blist[p] = (e << 12) | (d << 6) | s;
    }
}

// ---------------- K1: TCN conv1d(k=3,pad=1) + lin_l -> h[b][n][o] ----------------
__global__ __launch_bounds__(256) void k1_tcn_linl(
        const float* __restrict__ x, const float* __restrict__ tcn_w,
        const float* __restrict__ tcn_b, const float* __restrict__ lin_l_w,
        const float* __restrict__ lin_l_b, float* __restrict__ h)
{
    __shared__ float xs[130*65];
    __shared__ float xg[32*132];
    const int b = blockIdx.x, half = blockIdx.y, t = threadIdx.x;
    const int n0 = half * 32;

    for (int idx = t; idx < 8192; idx += 256) {
        int w = idx >> 6, i = idx & 63;
        xs[(w+1)*65 + i] = x[b*8192 + idx];
    }
    if (t < 65) { xs[t] = 0.f; xs[129*65 + t] = 0.f; }
    __syncthreads();

    {   // phase 1: conv
        const int nl = t >> 3;
        const int n  = n0 + nl;
        const int w0 = (t & 7) * 16;
        float acc[16];
        const float tb = tcn_b[n];
#pragma unroll
        for (int j = 0; j < 16; ++j) acc[j] = tb;
        for (int i = 0; i < 64; ++i) {
            const float t0 = tcn_w[n*192 + 3*i + 0];
            const float t1 = tcn_w[n*192 + 3*i + 1];
            const float t2 = tcn_w[n*192 + 3*i + 2];
            float a = xs[(w0+0)*65 + i];
            float c0 = xs[(w0+1)*65 + i];
#pragma unroll
            for (int dw = 0; dw < 16; ++dw) {
                float c = xs[(w0+dw+2)*65 + i];
                acc[dw] += a*t0 + c0*t1 + c*t2;
                a = c0; c0 = c;
            }
        }
#pragma unroll
        for (int dw = 0; dw < 16; ++dw) xg[nl*132 + w0 + dw] = acc[dw];
    }
    __syncthreads();

    {   // phase 2: 2 o x 8 n register tile
        const int o2 = t & 63, ng = t >> 6;
        const int oA = o2, oB = o2 + 64;
        float accA[8], accB[8];
        const float lbA = lin_l_b[oA], lbB = lin_l_b[oB];
#pragma unroll
        for (int j = 0; j < 8; ++j) { accA[j] = lbA; accB[j] = lbB; }
        for (int c = 0; c < 32; ++c) {
            const float4 lwA = *(const float4*)&lin_l_w[oA*128 + c*4];
            const float4 lwB = *(const float4*)&lin_l_w[oB*128 + c*4];
#pragma unroll
            for (int nn = 0; nn < 8; ++nn) {
                const float4 xv = *(const float4*)&xg[(ng*8+nn)*132 + c*4];
                accA[nn] += xv.x*lwA.x + xv.y*lwA.y + xv.z*lwA.z + xv.w*lwA.w;
                accB[nn] += xv.x*lwB.x + xv.y*lwB.y + xv.z*lwB.z + xv.w*lwB.w;
            }
        }
#pragma unroll
        for (int nn = 0; nn < 8; ++nn) {
            const int n = n0 + ng*8 + nn;
            h[(b*64 + n)*128 + oA] = accA[nn];
            h[(b*64 + n)*128 + oB] = accB[nn];
        }
    }
}

// ---------------- K2F: fused scores + softmax + P-build + P@H aggregation --------
// grid (128 b, 4 node-quarters of 16), 512 threads = 8 waves, 2 blocks/CU.
#define CAPQ 1280
__global__ __launch_bounds__(512, 2) void k2_fused(
        const float* __restrict__ hbase, const float* __restrict__ ea,
        const float* __restrict__ lin_e_w, const float* __restrict__ lin_e_b,
        const float* __restrict__ att, const int* __restrict__ bstart,
        const int* __restrict__ blist, u16* __restrict__ xgb)
{
    __shared__ float hbuf[64*132];      // h + 0.5*lin_e_b folded       33.8 KB
    __shared__ float scl[CAPQ*4];       // scores (then exp) per edge   20.5 KB
    __shared__ float Pm[4][16][68];     // alpha matrix per head        17.4 KB
    __shared__ int   bst[17];
    const int b = blockIdx.x, q = blockIdx.y, t = threadIdx.x;
    const int lane = t & 63, wv = t >> 6, l32 = lane & 31, h5 = lane >> 5;

    // ---- stage ----
    for (int idx = t; idx < 8192; idx += 512) {
        const int o = idx & 127;
        hbuf[(idx>>7)*132 + o] = hbase[(size_t)b*8192 + idx] + 0.5f*lin_e_b[o];
    }
    for (int idx = t; idx < 4*16*68; idx += 512) ((float*)Pm)[idx] = 0.f;
    if (t < 17) bst[t] = bstart[q*16 + t];
    // A-frags (lin_e_w rows = o) hi/lo and att into VGPRs
    bf16x8 Ah[4], Al[4];
#pragma unroll
    for (int mt = 0; mt < 4; ++mt) {
        const float* wp = &lin_e_w[(mt*32 + l32)*16 + h5*8];
        const float4 w0 = *(const float4*)wp;
        const float4 w1 = *(const float4*)(wp + 4);
        u16 th[8], tl[8];
        hilo(w0.x,&th[0],&tl[0]); hilo(w0.y,&th[1],&tl[1]);
        hilo(w0.z,&th[2],&tl[2]); hilo(w0.w,&th[3],&tl[3]);
        hilo(w1.x,&th[4],&tl[4]); hilo(w1.y,&th[5],&tl[5]);
        hilo(w1.z,&th[6],&tl[6]); hilo(w1.w,&th[7],&tl[7]);
        u16x8 vh = { th[0],th[1],th[2],th[3],th[4],th[5],th[6],th[7] };
        u16x8 vl = { tl[0],tl[1],tl[2],tl[3],tl[4],tl[5],tl[6],tl[7] };
        Ah[mt] = *(bf16x8*)&vh;
        Al[mt] = *(bf16x8*)&vl;
    }
    float4 attv[4][4];
#pragma unroll
    for (int mt = 0; mt < 4; ++mt)
#pragma unroll
        for (int g = 0; g < 4; ++g)
            attv[mt][g] = *(const float4*)&att[mt*32 + g*8 + h5*4];
    __syncthreads();

    const int lo = bst[0], cnt = min(bst[16] - lo, CAPQ);
    const int gcnt = (cnt + 31) >> 5;

    // ---- phase 1: scores (bucket-ordered edges; hd near-broadcast) ----
    for (int g = wv; g < gcnt; g += 8) {
        const int idx = g*32 + l32;
        const bool valid = idx < cnt;
        const int pk = valid ? blist[lo + idx] : 0;
        const int sn = pk & 63, dd = (pk >> 6) & 63, e = pk >> 12;
        const float* eap = ea + ((size_t)b*NE + e)*16 + h5*8;
        const float4 v0 = *(const float4*)eap;
        const float4 v1 = *(const float4*)(eap + 4);
        u16 bh[8], bl[8];
        hilo(v0.x,&bh[0],&bl[0]); hilo(v0.y,&bh[1],&bl[1]);
        hilo(v0.z,&bh[2],&bl[2]); hilo(v0.w,&bh[3],&bl[3]);
        hilo(v1.x,&bh[4],&bl[4]); hilo(v1.y,&bh[5],&bl[5]);
        hilo(v1.z,&bh[6],&bl[6]); hilo(v1.w,&bh[7],&bl[7]);
        u16x8 vbh = { bh[0],bh[1],bh[2],bh[3],bh[4],bh[5],bh[6],bh[7] };
        u16x8 vbl = { bl[0],bl[1],bl[2],bl[3],bl[4],bl[5],bl[6],bl[7] };
        const bf16x8 Bh = *(bf16x8*)&vbh;
        const bf16x8 Bl = *(bf16x8*)&vbl;
        float hacc[4];
#pragma unroll
        for (int mt = 0; mt < 4; ++mt) {
            f32x16 D = {0.f,0.f,0.f,0.f,0.f,0.f,0.f,0.f,
                        0.f,0.f,0.f,0.f,0.f,0.f,0.f,0.f};
            D = __builtin_amdgcn_mfma_f32_32x32x16_bf16(Al[mt], Bh, D, 0, 0, 0);
            D = __builtin_amdgcn_mfma_f32_32x32x16_bf16(Ah[mt], Bl, D, 0, 0, 0);
            D = __builtin_amdgcn_mfma_f32_32x32x16_bf16(Ah[mt], Bh, D, 0, 0, 0);
            float s = 0.f;
#pragma unroll
            for (int g4 = 0; g4 < 4; ++g4) {
                const int ob = mt*32 + g4*8 + h5*4;
                const float4 hd = *(const float4*)&hbuf[dd*132 + ob];
                const float4 hs = *(const float4*)&hbuf[sn*132 + ob];
                float x0 = hd.x + hs.x + D[g4*4+0];
                float x1 = hd.y + hs.y + D[g4*4+1];
                float x2 = hd.z + hs.z + D[g4*4+2];
                float x3 = hd.w + hs.w + D[g4*4+3];
                x0 = fmaxf(x0, 0.01f*x0); x1 = fmaxf(x1, 0.01f*x1);
                x2 = fmaxf(x2, 0.01f*x2); x3 = fmaxf(x3, 0.01f*x3);
                const float4 a4 = attv[mt][g4];
                s += a4.x*x0 + a4.y*x1 + a4.z*x2 + a4.w*x3;
            }
            hacc[mt] = s;
        }
#pragma unroll
        for (int hh = 0; hh < 4; ++hh)
            hacc[hh] += __shfl_xor(hacc[hh], 32);
        if (h5 == 0 && valid)
            *(float4*)&scl[idx*4] = make_float4(hacc[0], hacc[1], hacc[2], hacc[3]);
    }
    __syncthreads();

    // ---- phase 2: softmax stats + P scatter (64 pairs x 8 subs) ----
    {
        const int pair = t >> 3, sub = t & 7;   // 64 pairs = 16 nodes x 4 heads
        const int nl = pair >> 2, hh = pair & 3;
        const int s0 = bst[nl] - lo, s1 = bst[nl+1] - lo;
        float mx = -3.4e38f;
        for (int i = s0 + sub; i < s1; i += 8) mx = fmaxf(mx, scl[i*4 + hh]);
        mx = fmaxf(mx, __shfl_xor(mx, 1));
        mx = fmaxf(mx, __shfl_xor(mx, 2));
        mx = fmaxf(mx, __shfl_xor(mx, 4));
        float den = 0.f;
        for (int i = s0 + sub; i < s1; i += 8) {
            const float ex = __expf(scl[i*4 + hh] - mx);
            scl[i*4 + hh] = ex;
            den += ex;
        }
        den += __shfl_xor(den, 1);
        den += __shfl_xor(den, 2);
        den += __shfl_xor(den, 4);
        const float rd = 1.0f / (den + 1e-16f);
        for (int i = s0 + sub; i < s1; i += 8) {
            const int src = blist[lo + i] & 63;
            atomicAdd(&Pm[hh][nl][src], scl[i*4 + hh] * rd);
        }
    }
    __syncthreads();

    // ---- phase 3: xgat[16 nodes][128 o] = P @ H, 16x16x32 MFMA, all 8 waves ----
    {
        const int o0 = wv*16;                // 8 waves x 16 o-columns
        const int hh = wv >> 1;              // head for this o-range
        const int quad = lane >> 4, l16 = lane & 15;
        f32x4 D = (f32x4){0.f, 0.f, 0.f, 0.f};
#pragma unroll
        for (int k0 = 0; k0 < 64; k0 += 32) {
            u16 ph[8], pl[8], bhv[8], blv[8];
#pragma unroll
            for (int j = 0; j < 8; ++j) {
                const int k = k0 + quad*8 + j;
                hilo(Pm[hh][l16][k], &ph[j], &pl[j]);
                hilo(hbuf[k*132 + o0 + l16], &bhv[j], &blv[j]);
            }
            u16x8 vph = { ph[0],ph[1],ph[2],ph[3],ph[4],ph[5],ph[6],ph[7] };
            u16x8 vpl = { pl[0],pl[1],pl[2],pl[3],pl[4],pl[5],pl[6],pl[7] };
            u16x8 vbh = { bhv[0],bhv[1],bhv[2],bhv[3],bhv[4],bhv[5],bhv[6],bhv[7] };
            u16x8 vbl = { blv[0],blv[1],blv[2],blv[3],blv[4],blv[5],blv[6],blv[7] };
            const bf16x8 Ph = *(bf16x8*)&vph, Pl = *(bf16x8*)&vpl;
            const bf16x8 Hh = *(bf16x8*)&vbh, Hl = *(bf16x8*)&vbl;
            D = __builtin_amdgcn_mfma_f32_16x16x32_bf16(Pl, Hh, D, 0, 0, 0);
            D = __builtin_amdgcn_mfma_f32_16x16x32_bf16(Ph, Hl, D, 0, 0, 0);
            D = __builtin_amdgcn_mfma_f32_16x16x32_bf16(Ph, Hh, D, 0, 0, 0);
        }
        // D: col(o-local) = l16, row(node-local m) = quad*4 + r
        const int o = o0 + l16;
        const float lb2 = 0.5f * lin_e_b[o];
#pragma unroll
        for (int r = 0; r < 4; ++r) {
            const int m = quad*4 + r;
            const float corr = (bst[m+1] > bst[m]) ? lb2 : 0.f;
            float v = D[r] - corr;
            v = v > 0.f ? v : expm1f(v);
            xgb[(size_t)b*8192 + (q*16 + m)*128 + o] = f2bf(v);
        }
    }
}

// ---------------- K3: fc1 via bf16 MFMA; 16-wide j-tiles, 4 blocks/CU ------------
// grid (128 j-tiles of 16, 8 k-splits of 1024), 256 threads = 4 waves.
__global__ __launch_bounds__(256, 4) void k3_fc1(
        const u16* __restrict__ xgb, const float* __restrict__ fc1_w,
        float* __restrict__ part)
{
    __shared__ u16 Ash[128*72];
    __shared__ u16 Bsh[16*72];
    const int jb = blockIdx.x, ks = blockIdx.y, t = threadIdx.x;
    const int j0 = jb*16, k0 = ks*1024;
    const int wave = t >> 6, lane = t & 63;
    const int quad = lane >> 4, l16 = lane & 15;
    const int wm = wave * 32;

    f32x4 acc[2];
#pragma unroll
    for (int i = 0; i < 2; ++i) acc[i] = (f32x4){0.f, 0.f, 0.f, 0.f};

    const int arow = t >> 1, acol = (t & 1) * 32;    // A: 128 rows x 64 k (bf16 copy)
    const int brow = t >> 4, bcol = (t & 15) * 4;    // B: 16 rows x 64 k (fp32->bf16)

    for (int kc = 0; kc < 1024; kc += 64) {
        if (kc) __syncthreads();
        const u16* ap = xgb + (size_t)arow*FLATD + k0 + kc + acol;
#pragma unroll
        for (int qq = 0; qq < 4; ++qq)
            *(u16x8*)&Ash[arow*72 + acol + qq*8] = *(const u16x8*)(ap + qq*8);
        const float* bp = fc1_w + (size_t)(j0 + brow)*FLATD + k0 + kc + bcol;
        {
            float4 v = *(const float4*)bp;
            u16x4 u = { f2bf(v.x), f2bf(v.y), f2bf(v.z), f2bf(v.w) };
            *(u16x4*)&Bsh[brow*72 + bcol] = u;
        }
        __syncthreads();
#pragma unroll
        for (int kk = 0; kk < 64; kk += 32) {
            bf16x8 af[2], bfr;
#pragma unroll
            for (int i = 0; i < 2; ++i)
                af[i] = *(const bf16x8*)&Ash[(wm + i*16 + l16)*72 + kk + quad*8];
            bfr = *(const bf16x8*)&Bsh[l16*72 + kk + quad*8];
#pragma unroll
            for (int i = 0; i < 2; ++i)
                acc[i] = __builtin_amdgcn_mfma_f32_16x16x32_bf16(af[i], bfr, acc[i], 0, 0, 0);
        }
    }
#pragma unroll
    for (int i = 0; i < 2; ++i) {
        const int n = j0 + l16;
#pragma unroll
        for (int r = 0; r < 4; ++r) {
            const int m = wm + i*16 + quad*4 + r;
            part[(size_t)ks*262144 + (size_t)m*HIDD + n] = acc[i][r];
        }
    }
}

// ---------------- K4: reduce partials + bias + BN + relu + fc2 (j-split x4) ------
__global__ __launch_bounds__(256) void k4_fc2(
        const float* __restrict__ part, const float* __restrict__ fc1_b,
        const float* __restrict__ bn_g, const float* __restrict__ bn_b,
        const float* __restrict__ fc2_w, const float* __restrict__ fc2_b,
        float* __restrict__ out)
{
    __shared__ float r0[256], r1[256];
    const int b = blockIdx.x, jq = blockIdx.y, t = threadIdx.x;
    const float inv = 1.0f / sqrtf(1.0f + 1e-5f);
    float p0 = 0.f, p1 = 0.f;
#pragma unroll
    for (int jj = 0; jj < 2; ++jj) {
        const int j = jq*512 + jj*256 + t;
        float hv = 0.f;
#pragma unroll
        for (int s = 0; s < 8; ++s) hv += part[(size_t)s*262144 + (size_t)b*2048 + j];
        float v = (hv + fc1_b[j]) * (bn_g[j] * inv) + bn_b[j];
        v = fmaxf(v, 0.f);
        p0 += v * fc2_w[j];
        p1 += v * fc2_w[2048 + j];
    }
    r0[t] = p0; r1[t] = p1;
    __syncthreads();
    for (int s = 128; s > 0; s >>= 1) {
        if (t < s) { r0[t] += r0[t+s]; r1[t] += r1[t+s]; }
        __syncthreads();
    }
    if (t == 0) {
        const float b0 = (jq == 0) ? fc2_b[0] : 0.f;
        const float b1 = (jq == 0) ? fc2_b[1] : 0.f;
        atomicAdd(&out[b*2 + 0], r0[0] + b0);
        atomicAdd(&out[b*2 + 1], r1[0] + b1);
    }
}

extern "C" void kernel_launch(void* const* d_in, const int* in_sizes, int n_in,
                              void* d_out, int out_size, void* d_ws, size_t ws_size,
                              hipStream_t stream)
{
    const float* x       = (const float*)d_in[0];
    const int*   ei      = (const int*)  d_in[1];
    const float* ea      = (const float*)d_in[2];
    const float* tcn_w   = (const float*)d_in[3];
    const float* tcn_b   = (const float*)d_in[4];
    const float* lin_l_w = (const float*)d_in[5];
    const float* lin_l_b = (const float*)d_in[6];
    const float* lin_e_w = (const float*)d_in[7];
    const float* lin_e_b = (const float*)d_in[8];
    const float* att     = (const float*)d_in[9];
    const float* fc1_w   = (const float*)d_in[10];
    const float* fc1_b   = (const float*)d_in[11];
    const float* bn_g    = (const float*)d_in[12];
    const float* bn_b    = (const float*)d_in[13];
    const float* fc2_w   = (const float*)d_in[14];
    const float* fc2_b   = (const float*)d_in[15];

    float* ws     = (float*)d_ws;
    float* hbuf   = ws + OFF_H;
    float* part   = ws + OFF_P;
    u16*   xgb    = (u16*)(ws + OFF_XGB);
    int*   bstart = (int*)(ws + OFF_BK);
    int*   blist  = bstart + 80;
    float* out    = (float*)d_out;

    hipMemsetAsync(out, 0, (size_t)out_size*sizeof(float), stream);

    k0_bucket  <<<1, 256, 0, stream>>>(ei, bstart, blist);
    k1_tcn_linl<<<dim3(BB, 2), 256, 0, stream>>>(x, tcn_w, tcn_b, lin_l_w, lin_l_b, hbuf);
    k2_fused   <<<dim3(BB, 4), 512, 0, stream>>>(hbuf, ea, lin_e_w, lin_e_b, att,
                                                 bstart, blist, xgb);
    k3_fc1     <<<dim3(128, 8), 256, 0, stream>>>(xgb, fc1_w, part);
    k4_fc2     <<<dim3(BB, 4), 256, 0, stream>>>(part, fc1_b, bn_g, bn_b, fc2_w, fc2_b, out);
}